// Round 19
// baseline (105.392 us; speedup 1.0000x reference)
//
#include <hip/hip_runtime.h>
#include <math.h>

namespace {

constexpr int kB  = 2;
constexpr int kC  = 256;
constexpr int kN  = 4096;   // 64*64 tokens
constexpr int kHD = 32;
constexpr int kC4 = 1024;

typedef __attribute__((ext_vector_type(8))) short bf16x8;
typedef __attribute__((ext_vector_type(4))) float f32x4;
typedef __attribute__((ext_vector_type(16))) float f32x16;

__device__ __forceinline__ float gelu_exact(float x) {
  return 0.5f * x * (1.0f + erff(x * 0.70710678118654752f));
}

// f32 -> bf16 RNE (scalar)
__device__ __forceinline__ unsigned short f2bf(float x) {
  unsigned u = __builtin_bit_cast(unsigned, x);
  u += 0x7FFFu + ((u >> 16) & 1u);
  return (unsigned short)(u >> 16);
}

// bf16 (as ushort) -> f32
__device__ __forceinline__ float bf2f(unsigned short us) {
  return __builtin_bit_cast(float, (unsigned)us << 16);
}

// hardware exp2 (trans pipe)
__device__ __forceinline__ float exp2_hw(float x) {
#if __has_builtin(__builtin_amdgcn_exp2f)
  return __builtin_amdgcn_exp2f(x);
#else
  float r;
  asm("v_exp_f32 %0, %1\n\ts_nop 1" : "=v"(r) : "v"(x));
  return r;
#endif
}

// pack two f32 -> one u32 of 2 bf16 via single HW op (T12)
__device__ __forceinline__ unsigned cvt_pk_bf16(float lo, float hi) {
  unsigned r;
  asm("v_cvt_pk_bf16_f32 %0, %1, %2" : "=v"(r) : "v"(lo), "v"(hi));
  return r;
}

// ---------------------------------------------------------------------------
// Merged convert: z<4 -> transpose-convert (B,C,N) f32 -> (B,N,C) bf16;
// z==4 -> all six weights f32->bf16.  grid (128, 8, 5) x 256.
__global__ __launch_bounds__(256)
void convert_all(const float* __restrict__ qfeat, const float* __restrict__ lfeat,
                 const float* __restrict__ Wq, const float* __restrict__ Wk,
                 const float* __restrict__ Wv, const float* __restrict__ Wo,
                 const float* __restrict__ W1, const float* __restrict__ W2,
                 unsigned short* __restrict__ qtok, unsigned short* __restrict__ ltok,
                 unsigned short* __restrict__ wbf)
{
  __shared__ float Lds[32][36];
  const int z = blockIdx.z;
  const int t = threadIdx.x;
  if (z < 4) {
    const float* src = (z < kB) ? qfeat : lfeat;
    unsigned short* dst = (z < kB) ? qtok : ltok;
    const int b = z & 1;
    src += (size_t)b * kC * kN;
    dst += (size_t)b * kN * kC;
    const int n0 = blockIdx.x * 32, c0 = blockIdx.y * 32;
    const int r = t >> 3, q4 = (t & 7) * 4;
    {
      const float4 v = *(const float4*)&src[(size_t)(c0 + r) * kN + n0 + q4];
      Lds[r][q4 + 0] = v.x; Lds[r][q4 + 1] = v.y; Lds[r][q4 + 2] = v.z; Lds[r][q4 + 3] = v.w;
    }
    __syncthreads();
    ushort4 p;
    p.x = f2bf(Lds[q4 + 0][r]); p.y = f2bf(Lds[q4 + 1][r]);
    p.z = f2bf(Lds[q4 + 2][r]); p.w = f2bf(Lds[q4 + 3][r]);
    *(ushort4*)&dst[(size_t)(n0 + r) * kC + c0 + q4] = p;
  } else {
    const int wi = blockIdx.y * 128 + blockIdx.x;
    if (wi >= 768) return;
    const int i4 = wi * 1024 + t * 4;
    const float* s; int base;
    if      (i4 < 65536)  { s = Wq; base = 0; }
    else if (i4 < 131072) { s = Wk; base = 65536; }
    else if (i4 < 196608) { s = Wv; base = 131072; }
    else if (i4 < 262144) { s = Wo; base = 196608; }
    else if (i4 < 524288) { s = W1; base = 262144; }
    else                  { s = W2; base = 524288; }
    const float4 v = *(const float4*)&s[i4 - base];
    ushort4 p;
    p.x = f2bf(v.x); p.y = f2bf(v.y); p.z = f2bf(v.z); p.w = f2bf(v.w);
    *(ushort4*)&wbf[i4] = p;
  }
}

// ---------------------------------------------------------------------------
// Fused Q + KV projection GEMM. grid (64, 12, 2): y<4 -> Q rows (M=256,
// scaled by qscale, token-major bf16 out); y>=4 -> K/V rows (M=512; rows<256
// -> K token-major, rows>=256 -> V channel-major). Tile 64x64, BK=64,
// double-buffered LDS, ONE barrier per K-step.
__global__ __launch_bounds__(256)
void gemm_qkv(const unsigned short* __restrict__ wbf,
              const unsigned short* __restrict__ qtok,
              const unsigned short* __restrict__ ltok,
              const float* __restrict__ bq, const float* __restrict__ bk,
              const float* __restrict__ bv,
              unsigned short* __restrict__ qout, unsigned short* __restrict__ kout,
              unsigned short* __restrict__ vout, float qscale)
{
  __shared__ unsigned short Wlds[2][64 * 64];
  __shared__ unsigned short Xlds[2][64 * 64];

  const int z = blockIdx.z;
  const bool isQ = blockIdx.y < 4;
  const int m0 = (isQ ? blockIdx.y : blockIdx.y - 4) * 64;
  const unsigned short* Wb = isQ ? wbf : (wbf + 65536);
  const unsigned short* Xt = (isQ ? qtok : ltok) + (size_t)z * kN * kC;

  const int t = threadIdx.x;
  const int w = t >> 6, l = t & 63;
  const int r = l & 15, g = l >> 4;
  const int wm = w >> 1, wn = w & 1;
  const int n0 = blockIdx.x * 64;

  const int rw = t >> 3;
  const int sw = (t & 7) ^ (rw & 7);
  const unsigned short* wsrc = Wb + (size_t)(m0 + rw) * kC + sw * 8;
  const unsigned short* xsrc = Xt + (size_t)(n0 + rw) * kC + sw * 8;

  f32x4 acc[2][2];
#pragma unroll
  for (int i = 0; i < 2; ++i)
#pragma unroll
    for (int j = 0; j < 2; ++j) acc[i][j] = {0.f, 0.f, 0.f, 0.f};

  bf16x8 wrg[2], xrg[2];
#pragma unroll
  for (int j = 0; j < 2; ++j) {
    wrg[j] = *(const bf16x8*)(wsrc + (size_t)(32 * j) * kC);
    xrg[j] = *(const bf16x8*)(xsrc + (size_t)(32 * j) * kC);
  }

  for (int it = 0; it < 4; ++it) {   // K = 256 = 4 x 64
    unsigned short* wl = &Wlds[it & 1][0];
    unsigned short* xl = &Xlds[it & 1][0];
    *(bf16x8*)((char*)wl + t * 16)         = wrg[0];
    *(bf16x8*)((char*)wl + (256 + t) * 16) = wrg[1];
    *(bf16x8*)((char*)xl + t * 16)         = xrg[0];
    *(bf16x8*)((char*)xl + (256 + t) * 16) = xrg[1];
    if (it + 1 < 4) {
      const int ko = (it + 1) * 64;
#pragma unroll
      for (int j = 0; j < 2; ++j) {
        wrg[j] = *(const bf16x8*)(wsrc + (size_t)(32 * j) * kC + ko);
        xrg[j] = *(const bf16x8*)(xsrc + (size_t)(32 * j) * kC + ko);
      }
    }
    __syncthreads();
#pragma unroll
    for (int kc = 0; kc < 2; ++kc) {
      const int sl = ((kc * 4 + g) ^ (r & 7)) * 16;
      bf16x8 a0 = *(const bf16x8*)((const char*)wl + (wm * 32 + r) * 128 + sl);
      bf16x8 a1 = *(const bf16x8*)((const char*)wl + (wm * 32 + 16 + r) * 128 + sl);
      bf16x8 b0 = *(const bf16x8*)((const char*)xl + (wn * 32 + r) * 128 + sl);
      bf16x8 b1 = *(const bf16x8*)((const char*)xl + (wn * 32 + 16 + r) * 128 + sl);
      acc[0][0] = __builtin_amdgcn_mfma_f32_16x16x32_bf16(a0, b0, acc[0][0], 0, 0, 0);
      acc[0][1] = __builtin_amdgcn_mfma_f32_16x16x32_bf16(a0, b1, acc[0][1], 0, 0, 0);
      acc[1][0] = __builtin_amdgcn_mfma_f32_16x16x32_bf16(a1, b0, acc[1][0], 0, 0, 0);
      acc[1][1] = __builtin_amdgcn_mfma_f32_16x16x32_bf16(a1, b1, acc[1][1], 0, 0, 0);
    }
  }

#pragma unroll
  for (int f = 0; f < 2; ++f) {
    const int mb = m0 + wm * 32 + f * 16 + 4 * g;
    const float* bp = isQ ? (bq + mb) : (mb < 256 ? (bk + mb) : (bv + mb - 256));
    const float4 b4 = *(const float4*)bp;
    const float os = isQ ? qscale : 1.0f;
#pragma unroll
    for (int fn = 0; fn < 2; ++fn) {
      const int n = n0 + wn * 32 + fn * 16 + r;
      float v[4];
      v[0] = (acc[f][fn][0] + b4.x) * os; v[1] = (acc[f][fn][1] + b4.y) * os;
      v[2] = (acc[f][fn][2] + b4.z) * os; v[3] = (acc[f][fn][3] + b4.w) * os;
      if (isQ) {
        unsigned short* Yt = qout + (size_t)z * kN * kC;
        ushort4 pk;
        pk.x = f2bf(v[0]); pk.y = f2bf(v[1]); pk.z = f2bf(v[2]); pk.w = f2bf(v[3]);
        *(ushort4*)&Yt[(size_t)n * kC + mb] = pk;
      } else if (mb < 256) {
        unsigned short* Yt = kout + (size_t)z * kN * kC;
        ushort4 pk;
        pk.x = f2bf(v[0]); pk.y = f2bf(v[1]); pk.z = f2bf(v[2]); pk.w = f2bf(v[3]);
        *(ushort4*)&Yt[(size_t)n * kC + mb] = pk;
      } else {
        unsigned short* Yc = vout + (size_t)z * kC * kN;
#pragma unroll
        for (int q = 0; q < 4; ++q) Yc[(size_t)(mb - 256 + q) * kN + n] = f2bf(v[q]);
      }
    }
  }
}

// ---------------------------------------------------------------------------
// MFMA GEMM, tile 64x64, BK=64, dbuf LDS (1 barrier/K-step), 4 waves.
// EPI: 1 = bf16 token-major Y1; optional f32 chan residual (RES)
//      6 = f32 chan Y1 + residual from bf16 token-major Y2
//      7 = bf16 token-major Y1 + residual from bf16 token-major Y2
template <int EPI, bool GELU, bool RES>
__global__ __launch_bounds__(256)
void gemm_mfma(const unsigned short* __restrict__ Wbf,
               const unsigned short* __restrict__ Xtok,
               const float* __restrict__ bias, const float* __restrict__ res,
               void* __restrict__ Y1, void* __restrict__ Y2,
               int M, int Nn, int K, float oscale)
{
  __shared__ unsigned short Wlds[2][64 * 64];
  __shared__ unsigned short Xlds[2][64 * 64];

  const int z = blockIdx.z;
  Xtok += (size_t)z * Nn * K;

  const int t = threadIdx.x;
  const int w = t >> 6, l = t & 63;
  const int r = l & 15, g = l >> 4;
  const int wm = w >> 1, wn = w & 1;
  const int m0 = blockIdx.y * 64, n0 = blockIdx.x * 64;

  const int rw = t >> 3;
  const int sw = (t & 7) ^ (rw & 7);
  const unsigned short* wsrc = Wbf + (size_t)(m0 + rw) * K + sw * 8;
  const unsigned short* xsrc = Xtok + (size_t)(n0 + rw) * K + sw * 8;

  f32x4 acc[2][2];
#pragma unroll
  for (int i = 0; i < 2; ++i)
#pragma unroll
    for (int j = 0; j < 2; ++j) acc[i][j] = {0.f, 0.f, 0.f, 0.f};

  bf16x8 wrg[2], xrg[2];
#pragma unroll
  for (int j = 0; j < 2; ++j) {
    wrg[j] = *(const bf16x8*)(wsrc + (size_t)(32 * j) * K);
    xrg[j] = *(const bf16x8*)(xsrc + (size_t)(32 * j) * K);
  }

  const int nit = K >> 6;
  for (int it = 0; it < nit; ++it) {
    unsigned short* wl = &Wlds[it & 1][0];
    unsigned short* xl = &Xlds[it & 1][0];
    *(bf16x8*)((char*)wl + t * 16)         = wrg[0];
    *(bf16x8*)((char*)wl + (256 + t) * 16) = wrg[1];
    *(bf16x8*)((char*)xl + t * 16)         = xrg[0];
    *(bf16x8*)((char*)xl + (256 + t) * 16) = xrg[1];
    if (it + 1 < nit) {
      const int ko = (it + 1) * 64;
#pragma unroll
      for (int j = 0; j < 2; ++j) {
        wrg[j] = *(const bf16x8*)(wsrc + (size_t)(32 * j) * K + ko);
        xrg[j] = *(const bf16x8*)(xsrc + (size_t)(32 * j) * K + ko);
      }
    }
    __syncthreads();
#pragma unroll
    for (int kc = 0; kc < 2; ++kc) {
      const int sl = ((kc * 4 + g) ^ (r & 7)) * 16;
      bf16x8 a0 = *(const bf16x8*)((const char*)wl + (wm * 32 + r) * 128 + sl);
      bf16x8 a1 = *(const bf16x8*)((const char*)wl + (wm * 32 + 16 + r) * 128 + sl);
      bf16x8 b0 = *(const bf16x8*)((const char*)xl + (wn * 32 + r) * 128 + sl);
      bf16x8 b1 = *(const bf16x8*)((const char*)xl + (wn * 32 + 16 + r) * 128 + sl);
      acc[0][0] = __builtin_amdgcn_mfma_f32_16x16x32_bf16(a0, b0, acc[0][0], 0, 0, 0);
      acc[0][1] = __builtin_amdgcn_mfma_f32_16x16x32_bf16(a0, b1, acc[0][1], 0, 0, 0);
      acc[1][0] = __builtin_amdgcn_mfma_f32_16x16x32_bf16(a1, b0, acc[1][0], 0, 0, 0);
      acc[1][1] = __builtin_amdgcn_mfma_f32_16x16x32_bf16(a1, b1, acc[1][1], 0, 0, 0);
    }
  }

#pragma unroll
  for (int f = 0; f < 2; ++f) {
    const int mb = m0 + wm * 32 + f * 16 + 4 * g;
    const float4 b4 = *(const float4*)&bias[mb];
#pragma unroll
    for (int fn = 0; fn < 2; ++fn) {
      const int n = n0 + wn * 32 + fn * 16 + r;
      float v[4];
      v[0] = (acc[f][fn][0] + b4.x) * oscale; v[1] = (acc[f][fn][1] + b4.y) * oscale;
      v[2] = (acc[f][fn][2] + b4.z) * oscale; v[3] = (acc[f][fn][3] + b4.w) * oscale;
      if (GELU) {
#pragma unroll
        for (int q = 0; q < 4; ++q) v[q] = gelu_exact(v[q]);
      }
      if (RES) {
#pragma unroll
        for (int q = 0; q < 4; ++q)
          v[q] += res[(size_t)z * M * Nn + (size_t)(mb + q) * Nn + n];
      }
      if constexpr (EPI == 7) {
        const unsigned short* Rt = (const unsigned short*)Y2 + (size_t)z * Nn * M;
        const ushort4 rr = *(const ushort4*)&Rt[(size_t)n * M + mb];
        v[0] += bf2f(rr.x); v[1] += bf2f(rr.y); v[2] += bf2f(rr.z); v[3] += bf2f(rr.w);
      }
      if constexpr (EPI == 1 || EPI == 7) {
        unsigned short* Yt = (unsigned short*)Y1 + (size_t)z * Nn * M;
        ushort4 pk;
        pk.x = f2bf(v[0]); pk.y = f2bf(v[1]); pk.z = f2bf(v[2]); pk.w = f2bf(v[3]);
        *(ushort4*)&Yt[(size_t)n * M + mb] = pk;
      }
      if constexpr (EPI == 6) {
        float* Yf = (float*)Y1 + (size_t)z * M * Nn;
        const unsigned short* Rt = (const unsigned short*)Y2 + (size_t)z * Nn * M;
#pragma unroll
        for (int q = 0; q < 4; ++q)
          Yf[(size_t)(mb + q) * Nn + n] = v[q] + bf2f(Rt[(size_t)n * M + mb + q]);
      }
    }
  }
}

// ---------------------------------------------------------------------------
// 32x32-MFMA flash attention, r14 block structure (512 thr = 8 waves =
// 4 q-groups x 2 K-halves, QBLK=128, 32 KB dbuf LDS, 60 VGPR) but each block
// covers only HALF the keys (part = (id>>4)&1) -> grid 1024 -> 4 blocks/CU
// -> 8 waves/SIMD (the clean high-occupancy config r15/r16 failed to reach).
// Blocks emit f32 partials (d-major, coalesced) + lsum; attn_combine reduces.
__global__ __launch_bounds__(512, 4)
void attn_part(const unsigned short* __restrict__ Qbf,
               const unsigned short* __restrict__ Kbf,
               const unsigned short* __restrict__ Vbf,
               float* __restrict__ partO, float* __restrict__ partL)
{
  __shared__ __attribute__((aligned(16))) char smem[32768];

  const int id = blockIdx.x;               // 1024
  const int bh = id & 15;                  // XCD-friendly: 2 heads per XCD L2
  const int part = (id >> 4) & 1;          // K-part: keys [part*2048, +2048)
  const int qblk = id >> 5;                // 0..31
  const int b = bh >> 3, hd = bh & 7;
  const int t = threadIdx.x;
  const int w = t >> 6, l = t & 63;
  const int r = l & 31, hi = l >> 5;
  const int qg = w >> 1, kh = w & 1;       // q-group, intra-part K-half

  const unsigned short* Qb = Qbf + (size_t)b * kN * kC;
  const unsigned short* Kb = Kbf + (size_t)b * kN * kC;
  const unsigned short* Vb = Vbf + ((size_t)b * kC + hd * kHD) * kN;

  const int q0 = qblk * 128 + qg * 32;

  const bf16x8 qf0 = *(const bf16x8*)&Qb[(size_t)(q0 + r) * kC + hd * kHD + hi * 8];
  const bf16x8 qf1 = *(const bf16x8*)&Qb[(size_t)(q0 + r) * kC + hd * kHD + 16 + hi * 8];

  // staging: threads [0,256) stage half 0, [256,512) half 1 of this part.
  const int tt = t & 255, th = t >> 8;
  const int kb0 = part * 2048 + th * 1024;
  const unsigned short* ksrc = Kb + (size_t)(kb0 + (tt >> 2)) * kC + hd * kHD + (tt & 3) * 8;
  const unsigned short* vsrc = Vb + (size_t)(tt >> 3) * kN + kb0 + (tt & 7) * 8;
  char* kdst = smem + th * 4096 + ((tt & 3) * 64 + ((tt >> 2) ^ (9 * (tt & 3)))) * 16;
  char* vdst = smem + 8192 + th * 4096 + ((tt & 7) * 32 + ((tt >> 3) ^ (tt & 7))) * 16;

  int koff[2][2], voff[2][2];
#pragma unroll
  for (int ds = 0; ds < 2; ++ds)
#pragma unroll
    for (int tile = 0; tile < 2; ++tile) {
      const int c = 2 * ds + hi;
      koff[ds][tile] = kh * 4096 + (c * 64 + tile * 32 + (r ^ (9 * c))) * 16;
    }
#pragma unroll
  for (int ktile = 0; ktile < 2; ++ktile)
#pragma unroll
    for (int kc = 0; kc < 2; ++kc) {
      const int c = ktile * 4 + kc * 2 + hi;
      voff[ktile][kc] = 8192 + kh * 4096 + (c * 32 + (r ^ c)) * 16;
    }

  const f32x16 ZV = {0.f};
  f32x16 oA = ZV, oB = ZV;
  float lsum = 0.f;

  bf16x8 krg = *(const bf16x8*)ksrc;
  bf16x8 vrg = *(const bf16x8*)vsrc;

  for (int it = 0; it < 16; ++it) {
    const int bo = (it & 1) << 14;         // double-buffer byte offset
    *(bf16x8*)(kdst + bo) = krg;
    *(bf16x8*)(vdst + bo) = vrg;
    if (it + 1 < 16) {
      krg = *(const bf16x8*)(ksrc + (size_t)(it + 1) * 64 * kC);
      vrg = *(const bf16x8*)(vsrc + (it + 1) * 64);
    }
    __syncthreads();

    bf16x8 ka00 = *(const bf16x8*)(smem + bo + koff[0][0]);
    bf16x8 ka10 = *(const bf16x8*)(smem + bo + koff[1][0]);
    bf16x8 ka01 = *(const bf16x8*)(smem + bo + koff[0][1]);
    bf16x8 ka11 = *(const bf16x8*)(smem + bo + koff[1][1]);
    __builtin_amdgcn_s_setprio(1);
    f32x16 s0 = __builtin_amdgcn_mfma_f32_32x32x16_bf16(ka00, qf0, ZV, 0, 0, 0);
    s0        = __builtin_amdgcn_mfma_f32_32x32x16_bf16(ka10, qf1, s0, 0, 0, 0);
    f32x16 s1 = __builtin_amdgcn_mfma_f32_32x32x16_bf16(ka01, qf0, ZV, 0, 0, 0);
    s1        = __builtin_amdgcn_mfma_f32_32x32x16_bf16(ka11, qf1, s1, 0, 0, 0);
    __builtin_amdgcn_s_setprio(0);

#pragma unroll
    for (int ktile = 0; ktile < 2; ++ktile) {
      const f32x16& sv = ktile ? s1 : s0;
      float pe[16];
#pragma unroll
      for (int j = 0; j < 16; ++j) pe[j] = exp2_hw(sv[j]);
      lsum += (((pe[0] + pe[1]) + (pe[2] + pe[3])) + ((pe[4] + pe[5]) + (pe[6] + pe[7])))
            + (((pe[8] + pe[9]) + (pe[10] + pe[11])) + ((pe[12] + pe[13]) + (pe[14] + pe[15])));
      const unsigned c0 = cvt_pk_bf16(pe[0], pe[1]),   c1 = cvt_pk_bf16(pe[2], pe[3]);
      const unsigned c2 = cvt_pk_bf16(pe[4], pe[5]),   c3 = cvt_pk_bf16(pe[6], pe[7]);
      const unsigned c4 = cvt_pk_bf16(pe[8], pe[9]),   c5 = cvt_pk_bf16(pe[10], pe[11]);
      const unsigned c6 = cvt_pk_bf16(pe[12], pe[13]), c7 = cvt_pk_bf16(pe[14], pe[15]);
      auto a02 = __builtin_amdgcn_permlane32_swap(c0, c2, false, false);
      auto a13 = __builtin_amdgcn_permlane32_swap(c1, c3, false, false);
      auto a46 = __builtin_amdgcn_permlane32_swap(c4, c6, false, false);
      auto a57 = __builtin_amdgcn_permlane32_swap(c5, c7, false, false);
      union { unsigned u[4]; bf16x8 v; } p0, p1;
      p0.u[0] = a02[0]; p0.u[1] = a13[0]; p0.u[2] = a02[1]; p0.u[3] = a13[1];
      p1.u[0] = a46[0]; p1.u[1] = a57[0]; p1.u[2] = a46[1]; p1.u[3] = a57[1];
      bf16x8 vf0 = *(const bf16x8*)(smem + bo + voff[ktile][0]);
      bf16x8 vf1 = *(const bf16x8*)(smem + bo + voff[ktile][1]);
      __builtin_amdgcn_s_setprio(1);
      oA = __builtin_amdgcn_mfma_f32_32x32x16_bf16(vf0, p0.v, oA, 0, 0, 0);
      oB = __builtin_amdgcn_mfma_f32_32x32x16_bf16(vf1, p1.v, oB, 0, 0, 0);
      __builtin_amdgcn_s_setprio(0);
    }
  }

  {
    auto pr = __builtin_amdgcn_permlane32_swap(
        __builtin_bit_cast(unsigned, lsum), __builtin_bit_cast(unsigned, lsum), false, false);
    lsum = __builtin_bit_cast(float, (unsigned)pr[0]) + __builtin_bit_cast(float, (unsigned)pr[1]);
  }
  float oS[16];
#pragma unroll
  for (int j = 0; j < 16; ++j) oS[j] = oA[j] + oB[j];

  // merge intra-part K-halves (Scr aliased over staging LDS)
  float* Scr = (float*)smem;               // [4][64][17]
  __syncthreads();                         // all waves done reading K/V LDS
  if (kh == 1) {
    float* S = Scr + ((size_t)qg * 64 + l) * 17;
#pragma unroll
    for (int j = 0; j < 16; ++j) S[j] = oS[j];
    S[16] = lsum;
  }
  __syncthreads();
  if (kh == 0) {
    const float* S = Scr + ((size_t)qg * 64 + l) * 17;
#pragma unroll
    for (int j = 0; j < 16; ++j) oS[j] += S[j];
    lsum += S[16];

    // write f32 partials, d-major (coalesced 128B runs along q)
    float* PO = partO + (((size_t)part * kB + b) * 8 + hd) * 32 * (size_t)kN;
#pragma unroll
    for (int j = 0; j < 16; ++j) {
      const int d = (j & 3) + 8 * (j >> 2) + 4 * hi;
      PO[(size_t)d * kN + q0 + r] = oS[j];
    }
    if (hi == 0)
      partL[(((size_t)part * kB + b) * 8 + hd) * (size_t)kN + q0 + r] = lsum;
  }
}

// ---------------------------------------------------------------------------
// Combine the two K-parts: o = (O0+O1)/(L0+L1), transpose to token-major bf16.
// grid (kN/64, 8, kB) x 256.
__global__ __launch_bounds__(256)
void attn_combine(const float* __restrict__ partO, const float* __restrict__ partL,
                  unsigned short* __restrict__ atok)
{
  __shared__ float Lds[32][72];
  const int b = blockIdx.z, hd = blockIdx.y, q0 = blockIdx.x * 64;
  const int t = threadIdx.x;

  const size_t o0 = (((size_t)0 * kB + b) * 8 + hd) * 32 * (size_t)kN;
  const size_t o1 = (((size_t)1 * kB + b) * 8 + hd) * 32 * (size_t)kN;
  const size_t l0 = (((size_t)0 * kB + b) * 8 + hd) * (size_t)kN;
  const size_t l1 = (((size_t)1 * kB + b) * 8 + hd) * (size_t)kN;

  const int d = t >> 3, q8 = (t & 7) * 8;
  {
    const float4 a0 = *(const float4*)&partO[o0 + (size_t)d * kN + q0 + q8];
    const float4 a1 = *(const float4*)&partO[o0 + (size_t)d * kN + q0 + q8 + 4];
    const float4 b0 = *(const float4*)&partO[o1 + (size_t)d * kN + q0 + q8];
    const float4 b1 = *(const float4*)&partO[o1 + (size_t)d * kN + q0 + q8 + 4];
    const float4 la0 = *(const float4*)&partL[l0 + q0 + q8];
    const float4 la1 = *(const float4*)&partL[l0 + q0 + q8 + 4];
    const float4 lb0 = *(const float4*)&partL[l1 + q0 + q8];
    const float4 lb1 = *(const float4*)&partL[l1 + q0 + q8 + 4];
    Lds[d][q8 + 0] = (a0.x + b0.x) / (la0.x + lb0.x);
    Lds[d][q8 + 1] = (a0.y + b0.y) / (la0.y + lb0.y);
    Lds[d][q8 + 2] = (a0.z + b0.z) / (la0.z + lb0.z);
    Lds[d][q8 + 3] = (a0.w + b0.w) / (la0.w + lb0.w);
    Lds[d][q8 + 4] = (a1.x + b1.x) / (la1.x + lb1.x);
    Lds[d][q8 + 5] = (a1.y + b1.y) / (la1.y + lb1.y);
    Lds[d][q8 + 6] = (a1.z + b1.z) / (la1.z + lb1.z);
    Lds[d][q8 + 7] = (a1.w + b1.w) / (la1.w + lb1.w);
  }
  __syncthreads();
  {
    const int q = t >> 2, c8 = (t & 3) * 8;
    ushort4 p0, p1;
    p0.x = f2bf(Lds[c8 + 0][q]); p0.y = f2bf(Lds[c8 + 1][q]);
    p0.z = f2bf(Lds[c8 + 2][q]); p0.w = f2bf(Lds[c8 + 3][q]);
    p1.x = f2bf(Lds[c8 + 4][q]); p1.y = f2bf(Lds[c8 + 5][q]);
    p1.z = f2bf(Lds[c8 + 6][q]); p1.w = f2bf(Lds[c8 + 7][q]);
    unsigned short* outp = atok + ((size_t)b * kN + q0 + q) * kC + hd * kHD + c8;
    *(ushort4*)outp = p0;
    *(ushort4*)(outp + 4) = p1;
  }
}

}  // namespace

extern "C" void kernel_launch(void* const* d_in, const int* in_sizes, int n_in,
                              void* d_out, int out_size, void* d_ws, size_t ws_size,
                              hipStream_t stream)
{
  const float* qfeat = (const float*)d_in[0];
  const float* lfeat = (const float*)d_in[1];
  const float* Wq = (const float*)d_in[2];
  const float* bq = (const float*)d_in[3];
  const float* Wk = (const float*)d_in[4];
  const float* bk = (const float*)d_in[5];
  const float* Wv = (const float*)d_in[6];
  const float* bv = (const float*)d_in[7];
  const float* Wo = (const float*)d_in[8];
  const float* bo = (const float*)d_in[9];
  const float* W1 = (const float*)d_in[10];
  const float* b1 = (const float*)d_in[11];
  const float* W2 = (const float*)d_in[12];
  const float* b2 = (const float*)d_in[13];
  float* out = (float*)d_out;
  (void)in_sizes; (void)n_in; (void)out_size; (void)ws_size;

  constexpr float kScaleLog2e = 0.25506970f;  // (1/sqrt(32)) * log2(e)

  const size_t bcn = (size_t)kB * kC * kN;  // 2,097,152
  unsigned short* qtok   = (unsigned short*)d_ws;   // bf16 (B,N,C) of query_feat
  unsigned short* ltok   = qtok + bcn;              // bf16 (B,N,C) of lateral_feat
  unsigned short* wbf    = ltok + bcn;              // bf16 weights, 786432
  unsigned short* qbf    = wbf + 786432;            // Q  bf16 (B,N,C), pre-scaled
  unsigned short* kbf    = qbf + bcn;               // K  bf16 (B,N,C)
  unsigned short* vbf    = kbf + bcn;               // V  bf16 (B,C,N)
  unsigned short* atok   = vbf + bcn;               // attn out bf16 (B,N,C)
  unsigned short* owstok = atok + bcn;              // attn block out bf16 (B,N,C)
  unsigned short* h1tok  = owstok + bcn;            // MLP hidden bf16 (B,N,4C)
  float*          partO  = (float*)(h1tok + (size_t)kB * kC4 * kN);  // [2][B][8][32][N]
  float*          partL  = partO + (size_t)2 * kB * 8 * 32 * kN;     // [2][B][8][N]

  dim3 blk(256);

  convert_all<<<dim3(128, 8, 5), blk, 0, stream>>>(
      qfeat, lfeat, Wq, Wk, Wv, Wo, W1, W2, qtok, ltok, wbf);

  // fused Q (pre-scaled) + K/V projections
  gemm_qkv<<<dim3(64, 12, 2), blk, 0, stream>>>(
      wbf, qtok, ltok, bq, bk, bv, qbf, kbf, vbf, kScaleLog2e);

  attn_part<<<dim3(1024), dim3(512), 0, stream>>>(qbf, kbf, vbf, partO, partL);
  attn_combine<<<dim3(64, 8, 2), blk, 0, stream>>>(partO, partL, atok);

  // O-proj + residual(qtok bf16) -> bf16 token-major
  gemm_mfma<7, false, false><<<dim3(64, 4, 2), blk, 0, stream>>>(
      wbf + 196608, atok, bo, nullptr, owstok, qtok, kC, kN, kC, 1.0f);
  gemm_mfma<1, true, false><<<dim3(64, 16, 2), blk, 0, stream>>>(
      wbf + 262144, owstok, b1, nullptr, h1tok, nullptr, kC4, kN, kC, 1.0f);
  // MLP2: f32 out + residual read from owstok (bf16 tok-major)
  gemm_mfma<6, false, false><<<dim3(64, 4, 2), blk, 0, stream>>>(
      wbf + 524288, h1tok, b2, nullptr, out, owstok, kC, kN, kC4, 1.0f);
}

// Round 20
// 104.000 us; speedup vs baseline: 1.0134x; 1.0134x over previous
//
#include <hip/hip_runtime.h>
#include <math.h>

namespace {

constexpr int kB  = 2;
constexpr int kC  = 256;
constexpr int kN  = 4096;   // 64*64 tokens
constexpr int kHD = 32;
constexpr int kC4 = 1024;

typedef __attribute__((ext_vector_type(8))) short bf16x8;
typedef __attribute__((ext_vector_type(4))) float f32x4;
typedef __attribute__((ext_vector_type(16))) float f32x16;

__device__ __forceinline__ float gelu_exact(float x) {
  return 0.5f * x * (1.0f + erff(x * 0.70710678118654752f));
}

// f32 -> bf16 RNE (scalar)
__device__ __forceinline__ unsigned short f2bf(float x) {
  unsigned u = __builtin_bit_cast(unsigned, x);
  u += 0x7FFFu + ((u >> 16) & 1u);
  return (unsigned short)(u >> 16);
}

// bf16 (as ushort) -> f32
__device__ __forceinline__ float bf2f(unsigned short us) {
  return __builtin_bit_cast(float, (unsigned)us << 16);
}

// hardware exp2 (trans pipe)
__device__ __forceinline__ float exp2_hw(float x) {
#if __has_builtin(__builtin_amdgcn_exp2f)
  return __builtin_amdgcn_exp2f(x);
#else
  float r;
  asm("v_exp_f32 %0, %1\n\ts_nop 1" : "=v"(r) : "v"(x));
  return r;
#endif
}

// pack two f32 -> one u32 of 2 bf16 via single HW op (T12)
__device__ __forceinline__ unsigned cvt_pk_bf16(float lo, float hi) {
  unsigned r;
  asm("v_cvt_pk_bf16_f32 %0, %1, %2" : "=v"(r) : "v"(lo), "v"(hi));
  return r;
}

// ---------------------------------------------------------------------------
// Merged convert: z<4 -> transpose-convert (B,C,N) f32 -> (B,N,C) bf16;
// z==4 -> all six weights f32->bf16.  grid (128, 8, 5) x 256.
__global__ __launch_bounds__(256)
void convert_all(const float* __restrict__ qfeat, const float* __restrict__ lfeat,
                 const float* __restrict__ Wq, const float* __restrict__ Wk,
                 const float* __restrict__ Wv, const float* __restrict__ Wo,
                 const float* __restrict__ W1, const float* __restrict__ W2,
                 unsigned short* __restrict__ qtok, unsigned short* __restrict__ ltok,
                 unsigned short* __restrict__ wbf)
{
  __shared__ float Lds[32][36];
  const int z = blockIdx.z;
  const int t = threadIdx.x;
  if (z < 4) {
    const float* src = (z < kB) ? qfeat : lfeat;
    unsigned short* dst = (z < kB) ? qtok : ltok;
    const int b = z & 1;
    src += (size_t)b * kC * kN;
    dst += (size_t)b * kN * kC;
    const int n0 = blockIdx.x * 32, c0 = blockIdx.y * 32;
    const int r = t >> 3, q4 = (t & 7) * 4;
    {
      const float4 v = *(const float4*)&src[(size_t)(c0 + r) * kN + n0 + q4];
      Lds[r][q4 + 0] = v.x; Lds[r][q4 + 1] = v.y; Lds[r][q4 + 2] = v.z; Lds[r][q4 + 3] = v.w;
    }
    __syncthreads();
    ushort4 p;
    p.x = f2bf(Lds[q4 + 0][r]); p.y = f2bf(Lds[q4 + 1][r]);
    p.z = f2bf(Lds[q4 + 2][r]); p.w = f2bf(Lds[q4 + 3][r]);
    *(ushort4*)&dst[(size_t)(n0 + r) * kC + c0 + q4] = p;
  } else {
    const int wi = blockIdx.y * 128 + blockIdx.x;
    if (wi >= 768) return;
    const int i4 = wi * 1024 + t * 4;
    const float* s; int base;
    if      (i4 < 65536)  { s = Wq; base = 0; }
    else if (i4 < 131072) { s = Wk; base = 65536; }
    else if (i4 < 196608) { s = Wv; base = 131072; }
    else if (i4 < 262144) { s = Wo; base = 196608; }
    else if (i4 < 524288) { s = W1; base = 262144; }
    else                  { s = W2; base = 524288; }
    const float4 v = *(const float4*)&s[i4 - base];
    ushort4 p;
    p.x = f2bf(v.x); p.y = f2bf(v.y); p.z = f2bf(v.z); p.w = f2bf(v.w);
    *(ushort4*)&wbf[i4] = p;
  }
}

// ---------------------------------------------------------------------------
// Fused Q + KV projection GEMM. grid (64, 12, 2): y<4 -> Q rows (M=256,
// scaled by qscale, token-major bf16 out); y>=4 -> K/V rows (M=512; rows<256
// -> K token-major, rows>=256 -> V channel-major). Tile 64x64, BK=64,
// double-buffered LDS, ONE barrier per K-step.
__global__ __launch_bounds__(256)
void gemm_qkv(const unsigned short* __restrict__ wbf,
              const unsigned short* __restrict__ qtok,
              const unsigned short* __restrict__ ltok,
              const float* __restrict__ bq, const float* __restrict__ bk,
              const float* __restrict__ bv,
              unsigned short* __restrict__ qout, unsigned short* __restrict__ kout,
              unsigned short* __restrict__ vout, float qscale)
{
  __shared__ unsigned short Wlds[2][64 * 64];
  __shared__ unsigned short Xlds[2][64 * 64];

  const int z = blockIdx.z;
  const bool isQ = blockIdx.y < 4;
  const int m0 = (isQ ? blockIdx.y : blockIdx.y - 4) * 64;
  const unsigned short* Wb = isQ ? wbf : (wbf + 65536);
  const unsigned short* Xt = (isQ ? qtok : ltok) + (size_t)z * kN * kC;

  const int t = threadIdx.x;
  const int w = t >> 6, l = t & 63;
  const int r = l & 15, g = l >> 4;
  const int wm = w >> 1, wn = w & 1;
  const int n0 = blockIdx.x * 64;

  const int rw = t >> 3;
  const int sw = (t & 7) ^ (rw & 7);
  const unsigned short* wsrc = Wb + (size_t)(m0 + rw) * kC + sw * 8;
  const unsigned short* xsrc = Xt + (size_t)(n0 + rw) * kC + sw * 8;

  f32x4 acc[2][2];
#pragma unroll
  for (int i = 0; i < 2; ++i)
#pragma unroll
    for (int j = 0; j < 2; ++j) acc[i][j] = {0.f, 0.f, 0.f, 0.f};

  bf16x8 wrg[2], xrg[2];
#pragma unroll
  for (int j = 0; j < 2; ++j) {
    wrg[j] = *(const bf16x8*)(wsrc + (size_t)(32 * j) * kC);
    xrg[j] = *(const bf16x8*)(xsrc + (size_t)(32 * j) * kC);
  }

  for (int it = 0; it < 4; ++it) {   // K = 256 = 4 x 64
    unsigned short* wl = &Wlds[it & 1][0];
    unsigned short* xl = &Xlds[it & 1][0];
    *(bf16x8*)((char*)wl + t * 16)         = wrg[0];
    *(bf16x8*)((char*)wl + (256 + t) * 16) = wrg[1];
    *(bf16x8*)((char*)xl + t * 16)         = xrg[0];
    *(bf16x8*)((char*)xl + (256 + t) * 16) = xrg[1];
    if (it + 1 < 4) {
      const int ko = (it + 1) * 64;
#pragma unroll
      for (int j = 0; j < 2; ++j) {
        wrg[j] = *(const bf16x8*)(wsrc + (size_t)(32 * j) * kC + ko);
        xrg[j] = *(const bf16x8*)(xsrc + (size_t)(32 * j) * kC + ko);
      }
    }
    __syncthreads();
#pragma unroll
    for (int kc = 0; kc < 2; ++kc) {
      const int sl = ((kc * 4 + g) ^ (r & 7)) * 16;
      bf16x8 a0 = *(const bf16x8*)((const char*)wl + (wm * 32 + r) * 128 + sl);
      bf16x8 a1 = *(const bf16x8*)((const char*)wl + (wm * 32 + 16 + r) * 128 + sl);
      bf16x8 b0 = *(const bf16x8*)((const char*)xl + (wn * 32 + r) * 128 + sl);
      bf16x8 b1 = *(const bf16x8*)((const char*)xl + (wn * 32 + 16 + r) * 128 + sl);
      acc[0][0] = __builtin_amdgcn_mfma_f32_16x16x32_bf16(a0, b0, acc[0][0], 0, 0, 0);
      acc[0][1] = __builtin_amdgcn_mfma_f32_16x16x32_bf16(a0, b1, acc[0][1], 0, 0, 0);
      acc[1][0] = __builtin_amdgcn_mfma_f32_16x16x32_bf16(a1, b0, acc[1][0], 0, 0, 0);
      acc[1][1] = __builtin_amdgcn_mfma_f32_16x16x32_bf16(a1, b1, acc[1][1], 0, 0, 0);
    }
  }

#pragma unroll
  for (int f = 0; f < 2; ++f) {
    const int mb = m0 + wm * 32 + f * 16 + 4 * g;
    const float* bp = isQ ? (bq + mb) : (mb < 256 ? (bk + mb) : (bv + mb - 256));
    const float4 b4 = *(const float4*)bp;
    const float os = isQ ? qscale : 1.0f;
#pragma unroll
    for (int fn = 0; fn < 2; ++fn) {
      const int n = n0 + wn * 32 + fn * 16 + r;
      float v[4];
      v[0] = (acc[f][fn][0] + b4.x) * os; v[1] = (acc[f][fn][1] + b4.y) * os;
      v[2] = (acc[f][fn][2] + b4.z) * os; v[3] = (acc[f][fn][3] + b4.w) * os;
      if (isQ) {
        unsigned short* Yt = qout + (size_t)z * kN * kC;
        ushort4 pk;
        pk.x = f2bf(v[0]); pk.y = f2bf(v[1]); pk.z = f2bf(v[2]); pk.w = f2bf(v[3]);
        *(ushort4*)&Yt[(size_t)n * kC + mb] = pk;
      } else if (mb < 256) {
        unsigned short* Yt = kout + (size_t)z * kN * kC;
        ushort4 pk;
        pk.x = f2bf(v[0]); pk.y = f2bf(v[1]); pk.z = f2bf(v[2]); pk.w = f2bf(v[3]);
        *(ushort4*)&Yt[(size_t)n * kC + mb] = pk;
      } else {
        unsigned short* Yc = vout + (size_t)z * kC * kN;
#pragma unroll
        for (int q = 0; q < 4; ++q) Yc[(size_t)(mb - 256 + q) * kN + n] = f2bf(v[q]);
      }
    }
  }
}

// ---------------------------------------------------------------------------
// MFMA GEMM, tile 64x64, BK=64, dbuf LDS (1 barrier/K-step), 4 waves.
// EPI: 1 = bf16 token-major Y1; optional f32 chan residual (RES)
//      6 = f32 chan Y1 + residual from bf16 token-major Y2
//      7 = bf16 token-major Y1 + residual from bf16 token-major Y2
template <int EPI, bool GELU, bool RES>
__global__ __launch_bounds__(256)
void gemm_mfma(const unsigned short* __restrict__ Wbf,
               const unsigned short* __restrict__ Xtok,
               const float* __restrict__ bias, const float* __restrict__ res,
               void* __restrict__ Y1, void* __restrict__ Y2,
               int M, int Nn, int K, float oscale)
{
  __shared__ unsigned short Wlds[2][64 * 64];
  __shared__ unsigned short Xlds[2][64 * 64];

  const int z = blockIdx.z;
  Xtok += (size_t)z * Nn * K;

  const int t = threadIdx.x;
  const int w = t >> 6, l = t & 63;
  const int r = l & 15, g = l >> 4;
  const int wm = w >> 1, wn = w & 1;
  const int m0 = blockIdx.y * 64, n0 = blockIdx.x * 64;

  const int rw = t >> 3;
  const int sw = (t & 7) ^ (rw & 7);
  const unsigned short* wsrc = Wbf + (size_t)(m0 + rw) * K + sw * 8;
  const unsigned short* xsrc = Xtok + (size_t)(n0 + rw) * K + sw * 8;

  f32x4 acc[2][2];
#pragma unroll
  for (int i = 0; i < 2; ++i)
#pragma unroll
    for (int j = 0; j < 2; ++j) acc[i][j] = {0.f, 0.f, 0.f, 0.f};

  bf16x8 wrg[2], xrg[2];
#pragma unroll
  for (int j = 0; j < 2; ++j) {
    wrg[j] = *(const bf16x8*)(wsrc + (size_t)(32 * j) * K);
    xrg[j] = *(const bf16x8*)(xsrc + (size_t)(32 * j) * K);
  }

  const int nit = K >> 6;
  for (int it = 0; it < nit; ++it) {
    unsigned short* wl = &Wlds[it & 1][0];
    unsigned short* xl = &Xlds[it & 1][0];
    *(bf16x8*)((char*)wl + t * 16)         = wrg[0];
    *(bf16x8*)((char*)wl + (256 + t) * 16) = wrg[1];
    *(bf16x8*)((char*)xl + t * 16)         = xrg[0];
    *(bf16x8*)((char*)xl + (256 + t) * 16) = xrg[1];
    if (it + 1 < nit) {
      const int ko = (it + 1) * 64;
#pragma unroll
      for (int j = 0; j < 2; ++j) {
        wrg[j] = *(const bf16x8*)(wsrc + (size_t)(32 * j) * K + ko);
        xrg[j] = *(const bf16x8*)(xsrc + (size_t)(32 * j) * K + ko);
      }
    }
    __syncthreads();
#pragma unroll
    for (int kc = 0; kc < 2; ++kc) {
      const int sl = ((kc * 4 + g) ^ (r & 7)) * 16;
      bf16x8 a0 = *(const bf16x8*)((const char*)wl + (wm * 32 + r) * 128 + sl);
      bf16x8 a1 = *(const bf16x8*)((const char*)wl + (wm * 32 + 16 + r) * 128 + sl);
      bf16x8 b0 = *(const bf16x8*)((const char*)xl + (wn * 32 + r) * 128 + sl);
      bf16x8 b1 = *(const bf16x8*)((const char*)xl + (wn * 32 + 16 + r) * 128 + sl);
      acc[0][0] = __builtin_amdgcn_mfma_f32_16x16x32_bf16(a0, b0, acc[0][0], 0, 0, 0);
      acc[0][1] = __builtin_amdgcn_mfma_f32_16x16x32_bf16(a0, b1, acc[0][1], 0, 0, 0);
      acc[1][0] = __builtin_amdgcn_mfma_f32_16x16x32_bf16(a1, b0, acc[1][0], 0, 0, 0);
      acc[1][1] = __builtin_amdgcn_mfma_f32_16x16x32_bf16(a1, b1, acc[1][1], 0, 0, 0);
    }
  }

#pragma unroll
  for (int f = 0; f < 2; ++f) {
    const int mb = m0 + wm * 32 + f * 16 + 4 * g;
    const float4 b4 = *(const float4*)&bias[mb];
#pragma unroll
    for (int fn = 0; fn < 2; ++fn) {
      const int n = n0 + wn * 32 + fn * 16 + r;
      float v[4];
      v[0] = (acc[f][fn][0] + b4.x) * oscale; v[1] = (acc[f][fn][1] + b4.y) * oscale;
      v[2] = (acc[f][fn][2] + b4.z) * oscale; v[3] = (acc[f][fn][3] + b4.w) * oscale;
      if (GELU) {
#pragma unroll
        for (int q = 0; q < 4; ++q) v[q] = gelu_exact(v[q]);
      }
      if (RES) {
#pragma unroll
        for (int q = 0; q < 4; ++q)
          v[q] += res[(size_t)z * M * Nn + (size_t)(mb + q) * Nn + n];
      }
      if constexpr (EPI == 7) {
        const unsigned short* Rt = (const unsigned short*)Y2 + (size_t)z * Nn * M;
        const ushort4 rr = *(const ushort4*)&Rt[(size_t)n * M + mb];
        v[0] += bf2f(rr.x); v[1] += bf2f(rr.y); v[2] += bf2f(rr.z); v[3] += bf2f(rr.w);
      }
      if constexpr (EPI == 1 || EPI == 7) {
        unsigned short* Yt = (unsigned short*)Y1 + (size_t)z * Nn * M;
        ushort4 pk;
        pk.x = f2bf(v[0]); pk.y = f2bf(v[1]); pk.z = f2bf(v[2]); pk.w = f2bf(v[3]);
        *(ushort4*)&Yt[(size_t)n * M + mb] = pk;
      }
      if constexpr (EPI == 6) {
        float* Yf = (float*)Y1 + (size_t)z * M * Nn;
        const unsigned short* Rt = (const unsigned short*)Y2 + (size_t)z * Nn * M;
#pragma unroll
        for (int q = 0; q < 4; ++q)
          Yf[(size_t)(mb + q) * Nn + n] = v[q] + bf2f(Rt[(size_t)n * M + mb + q]);
      }
    }
  }
}

// ---------------------------------------------------------------------------
// 32x32-MFMA flash attention, r14 structure + 2-tile ILP: each barrier phase
// stages TWO independent 64-key tiles (A,B); all 8 S-MFMAs issue up front, so
// each wave carries two overlapping dependency chains (softmax A runs while
// B's MFMAs drain). Targets the dependency-latency diagnosis via ILP (TLP was
// proven useless in r12/r16/r19). __launch_bounds__(512) WITHOUT min-waves:
// natural VGPR (~150) without r15's forced-spill.
// Block = 512 thr = 8 waves: 4 q-groups x 2 K-halves. QBLK=128. grid = 512.
// LDS 64 KB: dbuf x [tileA 16KB | tileB 16KB]; tile = [K kh0|K kh1|V kh0|V kh1].
__global__ __launch_bounds__(512)
void attn_mfma32(const unsigned short* __restrict__ Qbf,
                 const unsigned short* __restrict__ Kbf,
                 const unsigned short* __restrict__ Vbf,
                 unsigned short* __restrict__ Aout)
{
  __shared__ __attribute__((aligned(16))) char smem[65536];

  const int id = blockIdx.x;
  const int bh = id & 15;                  // XCD-friendly: 2 heads per XCD L2
  const int b = bh >> 3, hd = bh & 7;
  const int t = threadIdx.x;
  const int w = t >> 6, l = t & 63;
  const int r = l & 31, hi = l >> 5;
  const int qg = w >> 1, kh = w & 1;       // q-group, K-half

  const unsigned short* Qb = Qbf + (size_t)b * kN * kC;
  const unsigned short* Kb = Kbf + (size_t)b * kN * kC;
  const unsigned short* Vb = Vbf + ((size_t)b * kC + hd * kHD) * kN;
  unsigned short* Ap = Aout + (size_t)b * kN * kC;

  const int q0 = (id >> 4) * 128 + qg * 32;

  const bf16x8 qf0 = *(const bf16x8*)&Qb[(size_t)(q0 + r) * kC + hd * kHD + hi * 8];
  const bf16x8 qf1 = *(const bf16x8*)&Qb[(size_t)(q0 + r) * kC + hd * kHD + 16 + hi * 8];

  // staging: threads [0,256) stage K-half 0, [256,512) K-half 1; per round
  // each thread moves 16B K + 16B V for tile A and for tile B.
  const int tt = t & 255, th = t >> 8;
  const unsigned short* ksrc = Kb + (size_t)(th * 2048 + (tt >> 2)) * kC + hd * kHD + (tt & 3) * 8;
  const unsigned short* vsrc = Vb + (size_t)(tt >> 3) * kN + th * 2048 + (tt & 7) * 8;
  char* kdst = smem + th * 4096 + ((tt & 3) * 64 + ((tt >> 2) ^ (9 * (tt & 3)))) * 16;
  char* vdst = smem + 8192 + th * 4096 + ((tt & 7) * 32 + ((tt >> 3) ^ (tt & 7))) * 16;

  int koff[2][2], voff[2][2];
#pragma unroll
  for (int ds = 0; ds < 2; ++ds)
#pragma unroll
    for (int tile = 0; tile < 2; ++tile) {
      const int c = 2 * ds + hi;
      koff[ds][tile] = kh * 4096 + (c * 64 + tile * 32 + (r ^ (9 * c))) * 16;
    }
#pragma unroll
  for (int ktile = 0; ktile < 2; ++ktile)
#pragma unroll
    for (int kc = 0; kc < 2; ++kc) {
      const int c = ktile * 4 + kc * 2 + hi;
      voff[ktile][kc] = 8192 + kh * 4096 + (c * 32 + (r ^ c)) * 16;
    }

  const f32x16 ZV = {0.f};
  f32x16 oA = ZV, oB = ZV;
  float lsum = 0.f;

  // softmax + PV for one 64-key tile whose S is (s0v,s1v), V at base `vb`
  auto softmax_pv = [&](const f32x16& s0v, const f32x16& s1v, int vb) {
#pragma unroll
    for (int ktile = 0; ktile < 2; ++ktile) {
      const f32x16& sv = ktile ? s1v : s0v;
      float pe[16];
#pragma unroll
      for (int j = 0; j < 16; ++j) pe[j] = exp2_hw(sv[j]);
      lsum += (((pe[0] + pe[1]) + (pe[2] + pe[3])) + ((pe[4] + pe[5]) + (pe[6] + pe[7])))
            + (((pe[8] + pe[9]) + (pe[10] + pe[11])) + ((pe[12] + pe[13]) + (pe[14] + pe[15])));
      const unsigned c0 = cvt_pk_bf16(pe[0], pe[1]),   c1 = cvt_pk_bf16(pe[2], pe[3]);
      const unsigned c2 = cvt_pk_bf16(pe[4], pe[5]),   c3 = cvt_pk_bf16(pe[6], pe[7]);
      const unsigned c4 = cvt_pk_bf16(pe[8], pe[9]),   c5 = cvt_pk_bf16(pe[10], pe[11]);
      const unsigned c6 = cvt_pk_bf16(pe[12], pe[13]), c7 = cvt_pk_bf16(pe[14], pe[15]);
      auto a02 = __builtin_amdgcn_permlane32_swap(c0, c2, false, false);
      auto a13 = __builtin_amdgcn_permlane32_swap(c1, c3, false, false);
      auto a46 = __builtin_amdgcn_permlane32_swap(c4, c6, false, false);
      auto a57 = __builtin_amdgcn_permlane32_swap(c5, c7, false, false);
      union { unsigned u[4]; bf16x8 v; } p0, p1;
      p0.u[0] = a02[0]; p0.u[1] = a13[0]; p0.u[2] = a02[1]; p0.u[3] = a13[1];
      p1.u[0] = a46[0]; p1.u[1] = a57[0]; p1.u[2] = a46[1]; p1.u[3] = a57[1];
      bf16x8 vf0 = *(const bf16x8*)(smem + vb + voff[ktile][0]);
      bf16x8 vf1 = *(const bf16x8*)(smem + vb + voff[ktile][1]);
      __builtin_amdgcn_s_setprio(1);
      oA = __builtin_amdgcn_mfma_f32_32x32x16_bf16(vf0, p0.v, oA, 0, 0, 0);
      oB = __builtin_amdgcn_mfma_f32_32x32x16_bf16(vf1, p1.v, oB, 0, 0, 0);
      __builtin_amdgcn_s_setprio(0);
    }
  };

  bf16x8 krgA = *(const bf16x8*)ksrc;
  bf16x8 vrgA = *(const bf16x8*)vsrc;
  bf16x8 krgB = *(const bf16x8*)(ksrc + (size_t)64 * kC);
  bf16x8 vrgB = *(const bf16x8*)(vsrc + 64);

  for (int rd = 0; rd < 16; ++rd) {        // 128 keys per round per K-half
    const int bo = (rd & 1) << 15;         // double-buffer byte offset
    *(bf16x8*)(kdst + bo) = krgA;
    *(bf16x8*)(vdst + bo) = vrgA;
    *(bf16x8*)(kdst + bo + 16384) = krgB;
    *(bf16x8*)(vdst + bo + 16384) = vrgB;
    if (rd + 1 < 16) {
      const unsigned short* kn = ksrc + (size_t)(rd + 1) * 128 * kC;
      const unsigned short* vn = vsrc + (rd + 1) * 128;
      krgA = *(const bf16x8*)kn;
      vrgA = *(const bf16x8*)vn;
      krgB = *(const bf16x8*)(kn + (size_t)64 * kC);
      vrgB = *(const bf16x8*)(vn + 64);
    }
    __syncthreads();

    // K fragments for BOTH tiles; all 8 S-MFMAs issued up front (2 chains)
    bf16x8 a00A = *(const bf16x8*)(smem + bo + koff[0][0]);
    bf16x8 a10A = *(const bf16x8*)(smem + bo + koff[1][0]);
    bf16x8 a01A = *(const bf16x8*)(smem + bo + koff[0][1]);
    bf16x8 a11A = *(const bf16x8*)(smem + bo + koff[1][1]);
    bf16x8 a00B = *(const bf16x8*)(smem + bo + 16384 + koff[0][0]);
    bf16x8 a10B = *(const bf16x8*)(smem + bo + 16384 + koff[1][0]);
    bf16x8 a01B = *(const bf16x8*)(smem + bo + 16384 + koff[0][1]);
    bf16x8 a11B = *(const bf16x8*)(smem + bo + 16384 + koff[1][1]);
    __builtin_amdgcn_s_setprio(1);
    f32x16 sA0 = __builtin_amdgcn_mfma_f32_32x32x16_bf16(a00A, qf0, ZV, 0, 0, 0);
    f32x16 sA1 = __builtin_amdgcn_mfma_f32_32x32x16_bf16(a01A, qf0, ZV, 0, 0, 0);
    f32x16 sB0 = __builtin_amdgcn_mfma_f32_32x32x16_bf16(a00B, qf0, ZV, 0, 0, 0);
    f32x16 sB1 = __builtin_amdgcn_mfma_f32_32x32x16_bf16(a01B, qf0, ZV, 0, 0, 0);
    sA0 = __builtin_amdgcn_mfma_f32_32x32x16_bf16(a10A, qf1, sA0, 0, 0, 0);
    sA1 = __builtin_amdgcn_mfma_f32_32x32x16_bf16(a11A, qf1, sA1, 0, 0, 0);
    sB0 = __builtin_amdgcn_mfma_f32_32x32x16_bf16(a10B, qf1, sB0, 0, 0, 0);
    sB1 = __builtin_amdgcn_mfma_f32_32x32x16_bf16(a11B, qf1, sB1, 0, 0, 0);
    __builtin_amdgcn_s_setprio(0);

    softmax_pv(sA0, sA1, bo);              // tile A (B's MFMAs drain under this)
    softmax_pv(sB0, sB1, bo + 16384);      // tile B
  }

  {
    auto pr = __builtin_amdgcn_permlane32_swap(
        __builtin_bit_cast(unsigned, lsum), __builtin_bit_cast(unsigned, lsum), false, false);
    lsum = __builtin_bit_cast(float, (unsigned)pr[0]) + __builtin_bit_cast(float, (unsigned)pr[1]);
  }
  float oS[16];
#pragma unroll
  for (int j = 0; j < 16; ++j) oS[j] = oA[j] + oB[j];

  float* Scr = (float*)smem;               // [4][64][17], aliased over staging
  __syncthreads();
  if (kh == 1) {
    float* S = Scr + ((size_t)qg * 64 + l) * 17;
#pragma unroll
    for (int j = 0; j < 16; ++j) S[j] = oS[j];
    S[16] = lsum;
  }
  __syncthreads();
  if (kh == 0) {
    const float* S = Scr + ((size_t)qg * 64 + l) * 17;
#pragma unroll
    for (int j = 0; j < 16; ++j) oS[j] += S[j];
    lsum += S[16];
    const float inv = 1.f / lsum;

    unsigned* T = (unsigned*)(Scr + (size_t)qg * 64 * 17);
#pragma unroll
    for (int p = 0; p < 8; ++p) {
      const int r2 = 4 * (p >> 1) + 2 * hi + (p & 1);
      T[r2 * 33 + r] = cvt_pk_bf16(oS[2 * p] * inv, oS[2 * p + 1] * inv);
    }
    unsigned v[8];
#pragma unroll
    for (int j = 0; j < 8; ++j) v[j] = T[(8 * hi + j) * 33 + r];
    unsigned short* outp = Ap + (size_t)(q0 + r) * kC + hd * kHD + hi * 16;
    uint4 w0{v[0], v[1], v[2], v[3]}, w1{v[4], v[5], v[6], v[7]};
    *(uint4*)outp = w0;
    *(uint4*)(outp + 8) = w1;
  }
}

}  // namespace

extern "C" void kernel_launch(void* const* d_in, const int* in_sizes, int n_in,
                              void* d_out, int out_size, void* d_ws, size_t ws_size,
                              hipStream_t stream)
{
  const float* qfeat = (const float*)d_in[0];
  const float* lfeat = (const float*)d_in[1];
  const float* Wq = (const float*)d_in[2];
  const float* bq = (const float*)d_in[3];
  const float* Wk = (const float*)d_in[4];
  const float* bk = (const float*)d_in[5];
  const float* Wv = (const float*)d_in[6];
  const float* bv = (const float*)d_in[7];
  const float* Wo = (const float*)d_in[8];
  const float* bo = (const float*)d_in[9];
  const float* W1 = (const float*)d_in[10];
  const float* b1 = (const float*)d_in[11];
  const float* W2 = (const float*)d_in[12];
  const float* b2 = (const float*)d_in[13];
  float* out = (float*)d_out;
  (void)in_sizes; (void)n_in; (void)out_size; (void)ws_size;

  constexpr float kScaleLog2e = 0.25506970f;  // (1/sqrt(32)) * log2(e)

  const size_t bcn = (size_t)kB * kC * kN;  // 2,097,152
  unsigned short* qtok   = (unsigned short*)d_ws;   // bf16 (B,N,C) of query_feat
  unsigned short* ltok   = qtok + bcn;              // bf16 (B,N,C) of lateral_feat
  unsigned short* wbf    = ltok + bcn;              // bf16 weights, 786432
  unsigned short* qbf    = wbf + 786432;            // Q  bf16 (B,N,C), pre-scaled
  unsigned short* kbf    = qbf + bcn;               // K  bf16 (B,N,C)
  unsigned short* vbf    = kbf + bcn;               // V  bf16 (B,C,N)
  unsigned short* atok   = vbf + bcn;               // attn out bf16 (B,N,C)
  unsigned short* owstok = atok + bcn;              // attn block out bf16 (B,N,C)
  unsigned short* h1tok  = owstok + bcn;            // MLP hidden bf16 (B,N,4C)

  dim3 blk(256);

  convert_all<<<dim3(128, 8, 5), blk, 0, stream>>>(
      qfeat, lfeat, Wq, Wk, Wv, Wo, W1, W2, qtok, ltok, wbf);

  // fused Q (pre-scaled) + K/V projections
  gemm_qkv<<<dim3(64, 12, 2), blk, 0, stream>>>(
      wbf, qtok, ltok, bq, bk, bv, qbf, kbf, vbf, kScaleLog2e);

  attn_mfma32<<<dim3(512), dim3(512), 0, stream>>>(qbf, kbf, vbf, atok);

  // O-proj + residual(qtok bf16) -> bf16 token-major
  gemm_mfma<7, false, false><<<dim3(64, 4, 2), blk, 0, stream>>>(
      wbf + 196608, atok, bo, nullptr, owstok, qtok, kC, kN, kC, 1.0f);
  gemm_mfma<1, true, false><<<dim3(64, 16, 2), blk, 0, stream>>>(
      wbf + 262144, owstok, b1, nullptr, h1tok, nullptr, kC4, kN, kC, 1.0f);
  // MLP2: f32 out + residual read from owstok (bf16 tok-major)
  gemm_mfma<6, false, false><<<dim3(64, 4, 2), blk, 0, stream>>>(
      wbf + 524288, h1tok, b2, nullptr, out, owstok, kC, kN, kC4, 1.0f);
}

// Round 21
// 99.814 us; speedup vs baseline: 1.0559x; 1.0419x over previous
//
#include <hip/hip_runtime.h>
#include <math.h>

namespace {

constexpr int kB  = 2;
constexpr int kC  = 256;
constexpr int kN  = 4096;   // 64*64 tokens
constexpr int kHD = 32;
constexpr int kC4 = 1024;

typedef __attribute__((ext_vector_type(8))) short bf16x8;
typedef __attribute__((ext_vector_type(4))) float f32x4;
typedef __attribute__((ext_vector_type(16))) float f32x16;

__device__ __forceinline__ float gelu_exact(float x) {
  return 0.5f * x * (1.0f + erff(x * 0.70710678118654752f));
}

// f32 -> bf16 RNE (scalar)
__device__ __forceinline__ unsigned short f2bf(float x) {
  unsigned u = __builtin_bit_cast(unsigned, x);
  u += 0x7FFFu + ((u >> 16) & 1u);
  return (unsigned short)(u >> 16);
}

// bf16 (as ushort) -> f32
__device__ __forceinline__ float bf2f(unsigned short us) {
  return __builtin_bit_cast(float, (unsigned)us << 16);
}

// hardware exp2 (trans pipe — overlaps VALU issue)
__device__ __forceinline__ float exp2_hw(float x) {
#if __has_builtin(__builtin_amdgcn_exp2f)
  return __builtin_amdgcn_exp2f(x);
#else
  float r;
  asm("v_exp_f32 %0, %1\n\ts_nop 1" : "=v"(r) : "v"(x));
  return r;
#endif
}

// pack two f32 -> one u32 of 2 bf16 via single HW op (T12)
__device__ __forceinline__ unsigned cvt_pk_bf16(float lo, float hi) {
  unsigned r;
  asm("v_cvt_pk_bf16_f32 %0, %1, %2" : "=v"(r) : "v"(lo), "v"(hi));
  return r;
}

// ---------------------------------------------------------------------------
// Merged convert: z<4 -> transpose-convert (B,C,N) f32 -> (B,N,C) bf16;
// z==4 -> all six weights f32->bf16.  grid (128, 8, 5) x 256.
__global__ __launch_bounds__(256)
void convert_all(const float* __restrict__ qfeat, const float* __restrict__ lfeat,
                 const float* __restrict__ Wq, const float* __restrict__ Wk,
                 const float* __restrict__ Wv, const float* __restrict__ Wo,
                 const float* __restrict__ W1, const float* __restrict__ W2,
                 unsigned short* __restrict__ qtok, unsigned short* __restrict__ ltok,
                 unsigned short* __restrict__ wbf)
{
  __shared__ float Lds[32][36];
  const int z = blockIdx.z;
  const int t = threadIdx.x;
  if (z < 4) {
    const float* src = (z < kB) ? qfeat : lfeat;
    unsigned short* dst = (z < kB) ? qtok : ltok;
    const int b = z & 1;
    src += (size_t)b * kC * kN;
    dst += (size_t)b * kN * kC;
    const int n0 = blockIdx.x * 32, c0 = blockIdx.y * 32;
    const int r = t >> 3, q4 = (t & 7) * 4;
    {
      const float4 v = *(const float4*)&src[(size_t)(c0 + r) * kN + n0 + q4];
      Lds[r][q4 + 0] = v.x; Lds[r][q4 + 1] = v.y; Lds[r][q4 + 2] = v.z; Lds[r][q4 + 3] = v.w;
    }
    __syncthreads();
    ushort4 p;
    p.x = f2bf(Lds[q4 + 0][r]); p.y = f2bf(Lds[q4 + 1][r]);
    p.z = f2bf(Lds[q4 + 2][r]); p.w = f2bf(Lds[q4 + 3][r]);
    *(ushort4*)&dst[(size_t)(n0 + r) * kC + c0 + q4] = p;
  } else {
    const int wi = blockIdx.y * 128 + blockIdx.x;
    if (wi >= 768) return;
    const int i4 = wi * 1024 + t * 4;
    const float* s; int base;
    if      (i4 < 65536)  { s = Wq; base = 0; }
    else if (i4 < 131072) { s = Wk; base = 65536; }
    else if (i4 < 196608) { s = Wv; base = 131072; }
    else if (i4 < 262144) { s = Wo; base = 196608; }
    else if (i4 < 524288) { s = W1; base = 262144; }
    else                  { s = W2; base = 524288; }
    const float4 v = *(const float4*)&s[i4 - base];
    ushort4 p;
    p.x = f2bf(v.x); p.y = f2bf(v.y); p.z = f2bf(v.z); p.w = f2bf(v.w);
    *(ushort4*)&wbf[i4] = p;
  }
}

// ---------------------------------------------------------------------------
// Fused Q + KV projection GEMM. grid (64, 12, 2): y<4 -> Q rows (M=256,
// scaled by qscale, token-major bf16 out); y>=4 -> K/V rows (M=512; rows<256
// -> K token-major, rows>=256 -> V channel-major). Tile 64x64, BK=64,
// double-buffered LDS, ONE barrier per K-step.
__global__ __launch_bounds__(256)
void gemm_qkv(const unsigned short* __restrict__ wbf,
              const unsigned short* __restrict__ qtok,
              const unsigned short* __restrict__ ltok,
              const float* __restrict__ bq, const float* __restrict__ bk,
              const float* __restrict__ bv,
              unsigned short* __restrict__ qout, unsigned short* __restrict__ kout,
              unsigned short* __restrict__ vout, float qscale)
{
  __shared__ unsigned short Wlds[2][64 * 64];
  __shared__ unsigned short Xlds[2][64 * 64];

  const int z = blockIdx.z;
  const bool isQ = blockIdx.y < 4;
  const int m0 = (isQ ? blockIdx.y : blockIdx.y - 4) * 64;
  const unsigned short* Wb = isQ ? wbf : (wbf + 65536);
  const unsigned short* Xt = (isQ ? qtok : ltok) + (size_t)z * kN * kC;

  const int t = threadIdx.x;
  const int w = t >> 6, l = t & 63;
  const int r = l & 15, g = l >> 4;
  const int wm = w >> 1, wn = w & 1;
  const int n0 = blockIdx.x * 64;

  const int rw = t >> 3;
  const int sw = (t & 7) ^ (rw & 7);
  const unsigned short* wsrc = Wb + (size_t)(m0 + rw) * kC + sw * 8;
  const unsigned short* xsrc = Xt + (size_t)(n0 + rw) * kC + sw * 8;

  f32x4 acc[2][2];
#pragma unroll
  for (int i = 0; i < 2; ++i)
#pragma unroll
    for (int j = 0; j < 2; ++j) acc[i][j] = {0.f, 0.f, 0.f, 0.f};

  bf16x8 wrg[2], xrg[2];
#pragma unroll
  for (int j = 0; j < 2; ++j) {
    wrg[j] = *(const bf16x8*)(wsrc + (size_t)(32 * j) * kC);
    xrg[j] = *(const bf16x8*)(xsrc + (size_t)(32 * j) * kC);
  }

  for (int it = 0; it < 4; ++it) {   // K = 256 = 4 x 64
    unsigned short* wl = &Wlds[it & 1][0];
    unsigned short* xl = &Xlds[it & 1][0];
    *(bf16x8*)((char*)wl + t * 16)         = wrg[0];
    *(bf16x8*)((char*)wl + (256 + t) * 16) = wrg[1];
    *(bf16x8*)((char*)xl + t * 16)         = xrg[0];
    *(bf16x8*)((char*)xl + (256 + t) * 16) = xrg[1];
    if (it + 1 < 4) {
      const int ko = (it + 1) * 64;
#pragma unroll
      for (int j = 0; j < 2; ++j) {
        wrg[j] = *(const bf16x8*)(wsrc + (size_t)(32 * j) * kC + ko);
        xrg[j] = *(const bf16x8*)(xsrc + (size_t)(32 * j) * kC + ko);
      }
    }
    __syncthreads();
#pragma unroll
    for (int kc = 0; kc < 2; ++kc) {
      const int sl = ((kc * 4 + g) ^ (r & 7)) * 16;
      bf16x8 a0 = *(const bf16x8*)((const char*)wl + (wm * 32 + r) * 128 + sl);
      bf16x8 a1 = *(const bf16x8*)((const char*)wl + (wm * 32 + 16 + r) * 128 + sl);
      bf16x8 b0 = *(const bf16x8*)((const char*)xl + (wn * 32 + r) * 128 + sl);
      bf16x8 b1 = *(const bf16x8*)((const char*)xl + (wn * 32 + 16 + r) * 128 + sl);
      acc[0][0] = __builtin_amdgcn_mfma_f32_16x16x32_bf16(a0, b0, acc[0][0], 0, 0, 0);
      acc[0][1] = __builtin_amdgcn_mfma_f32_16x16x32_bf16(a0, b1, acc[0][1], 0, 0, 0);
      acc[1][0] = __builtin_amdgcn_mfma_f32_16x16x32_bf16(a1, b0, acc[1][0], 0, 0, 0);
      acc[1][1] = __builtin_amdgcn_mfma_f32_16x16x32_bf16(a1, b1, acc[1][1], 0, 0, 0);
    }
  }

#pragma unroll
  for (int f = 0; f < 2; ++f) {
    const int mb = m0 + wm * 32 + f * 16 + 4 * g;
    const float* bp = isQ ? (bq + mb) : (mb < 256 ? (bk + mb) : (bv + mb - 256));
    const float4 b4 = *(const float4*)bp;
    const float os = isQ ? qscale : 1.0f;
#pragma unroll
    for (int fn = 0; fn < 2; ++fn) {
      const int n = n0 + wn * 32 + fn * 16 + r;
      float v[4];
      v[0] = (acc[f][fn][0] + b4.x) * os; v[1] = (acc[f][fn][1] + b4.y) * os;
      v[2] = (acc[f][fn][2] + b4.z) * os; v[3] = (acc[f][fn][3] + b4.w) * os;
      if (isQ) {
        unsigned short* Yt = qout + (size_t)z * kN * kC;
        ushort4 pk;
        pk.x = f2bf(v[0]); pk.y = f2bf(v[1]); pk.z = f2bf(v[2]); pk.w = f2bf(v[3]);
        *(ushort4*)&Yt[(size_t)n * kC + mb] = pk;
      } else if (mb < 256) {
        unsigned short* Yt = kout + (size_t)z * kN * kC;
        ushort4 pk;
        pk.x = f2bf(v[0]); pk.y = f2bf(v[1]); pk.z = f2bf(v[2]); pk.w = f2bf(v[3]);
        *(ushort4*)&Yt[(size_t)n * kC + mb] = pk;
      } else {
        unsigned short* Yc = vout + (size_t)z * kC * kN;
#pragma unroll
        for (int q = 0; q < 4; ++q) Yc[(size_t)(mb - 256 + q) * kN + n] = f2bf(v[q]);
      }
    }
  }
}

// ---------------------------------------------------------------------------
// MFMA GEMM, tile 64x64, BK=64, dbuf LDS (1 barrier/K-step), 4 waves.
// EPI: 1 = bf16 token-major Y1; optional f32 chan residual (RES)
//      6 = f32 chan Y1 + residual from bf16 token-major Y2
//      7 = bf16 token-major Y1 + residual from bf16 token-major Y2
template <int EPI, bool GELU, bool RES>
__global__ __launch_bounds__(256)
void gemm_mfma(const unsigned short* __restrict__ Wbf,
               const unsigned short* __restrict__ Xtok,
               const float* __restrict__ bias, const float* __restrict__ res,
               void* __restrict__ Y1, void* __restrict__ Y2,
               int M, int Nn, int K, float oscale)
{
  __shared__ unsigned short Wlds[2][64 * 64];
  __shared__ unsigned short Xlds[2][64 * 64];

  const int z = blockIdx.z;
  Xtok += (size_t)z * Nn * K;

  const int t = threadIdx.x;
  const int w = t >> 6, l = t & 63;
  const int r = l & 15, g = l >> 4;
  const int wm = w >> 1, wn = w & 1;
  const int m0 = blockIdx.y * 64, n0 = blockIdx.x * 64;

  const int rw = t >> 3;
  const int sw = (t & 7) ^ (rw & 7);
  const unsigned short* wsrc = Wbf + (size_t)(m0 + rw) * K + sw * 8;
  const unsigned short* xsrc = Xtok + (size_t)(n0 + rw) * K + sw * 8;

  f32x4 acc[2][2];
#pragma unroll
  for (int i = 0; i < 2; ++i)
#pragma unroll
    for (int j = 0; j < 2; ++j) acc[i][j] = {0.f, 0.f, 0.f, 0.f};

  bf16x8 wrg[2], xrg[2];
#pragma unroll
  for (int j = 0; j < 2; ++j) {
    wrg[j] = *(const bf16x8*)(wsrc + (size_t)(32 * j) * K);
    xrg[j] = *(const bf16x8*)(xsrc + (size_t)(32 * j) * K);
  }

  const int nit = K >> 6;
  for (int it = 0; it < nit; ++it) {
    unsigned short* wl = &Wlds[it & 1][0];
    unsigned short* xl = &Xlds[it & 1][0];
    *(bf16x8*)((char*)wl + t * 16)         = wrg[0];
    *(bf16x8*)((char*)wl + (256 + t) * 16) = wrg[1];
    *(bf16x8*)((char*)xl + t * 16)         = xrg[0];
    *(bf16x8*)((char*)xl + (256 + t) * 16) = xrg[1];
    if (it + 1 < nit) {
      const int ko = (it + 1) * 64;
#pragma unroll
      for (int j = 0; j < 2; ++j) {
        wrg[j] = *(const bf16x8*)(wsrc + (size_t)(32 * j) * K + ko);
        xrg[j] = *(const bf16x8*)(xsrc + (size_t)(32 * j) * K + ko);
      }
    }
    __syncthreads();
#pragma unroll
    for (int kc = 0; kc < 2; ++kc) {
      const int sl = ((kc * 4 + g) ^ (r & 7)) * 16;
      bf16x8 a0 = *(const bf16x8*)((const char*)wl + (wm * 32 + r) * 128 + sl);
      bf16x8 a1 = *(const bf16x8*)((const char*)wl + (wm * 32 + 16 + r) * 128 + sl);
      bf16x8 b0 = *(const bf16x8*)((const char*)xl + (wn * 32 + r) * 128 + sl);
      bf16x8 b1 = *(const bf16x8*)((const char*)xl + (wn * 32 + 16 + r) * 128 + sl);
      acc[0][0] = __builtin_amdgcn_mfma_f32_16x16x32_bf16(a0, b0, acc[0][0], 0, 0, 0);
      acc[0][1] = __builtin_amdgcn_mfma_f32_16x16x32_bf16(a0, b1, acc[0][1], 0, 0, 0);
      acc[1][0] = __builtin_amdgcn_mfma_f32_16x16x32_bf16(a1, b0, acc[1][0], 0, 0, 0);
      acc[1][1] = __builtin_amdgcn_mfma_f32_16x16x32_bf16(a1, b1, acc[1][1], 0, 0, 0);
    }
  }

#pragma unroll
  for (int f = 0; f < 2; ++f) {
    const int mb = m0 + wm * 32 + f * 16 + 4 * g;
    const float4 b4 = *(const float4*)&bias[mb];
#pragma unroll
    for (int fn = 0; fn < 2; ++fn) {
      const int n = n0 + wn * 32 + fn * 16 + r;
      float v[4];
      v[0] = (acc[f][fn][0] + b4.x) * oscale; v[1] = (acc[f][fn][1] + b4.y) * oscale;
      v[2] = (acc[f][fn][2] + b4.z) * oscale; v[3] = (acc[f][fn][3] + b4.w) * oscale;
      if (GELU) {
#pragma unroll
        for (int q = 0; q < 4; ++q) v[q] = gelu_exact(v[q]);
      }
      if (RES) {
#pragma unroll
        for (int q = 0; q < 4; ++q)
          v[q] += res[(size_t)z * M * Nn + (size_t)(mb + q) * Nn + n];
      }
      if constexpr (EPI == 7) {
        const unsigned short* Rt = (const unsigned short*)Y2 + (size_t)z * Nn * M;
        const ushort4 rr = *(const ushort4*)&Rt[(size_t)n * M + mb];
        v[0] += bf2f(rr.x); v[1] += bf2f(rr.y); v[2] += bf2f(rr.z); v[3] += bf2f(rr.w);
      }
      if constexpr (EPI == 1 || EPI == 7) {
        unsigned short* Yt = (unsigned short*)Y1 + (size_t)z * Nn * M;
        ushort4 pk;
        pk.x = f2bf(v[0]); pk.y = f2bf(v[1]); pk.z = f2bf(v[2]); pk.w = f2bf(v[3]);
        *(ushort4*)&Yt[(size_t)n * M + mb] = pk;
      }
      if constexpr (EPI == 6) {
        float* Yf = (float*)Y1 + (size_t)z * M * Nn;
        const unsigned short* Rt = (const unsigned short*)Y2 + (size_t)z * Nn * M;
#pragma unroll
        for (int q = 0; q < 4; ++q)
          Yf[(size_t)(mb + q) * Nn + n] = v[q] + bf2f(Rt[(size_t)n * M + mb + q]);
      }
    }
  }
}

// ---------------------------------------------------------------------------
// 32x32-MFMA flash attention (r14 configuration — empirical best across the
// r8..r20 design-space sweep; see commit log: occupancy/barrier/exp-pipe/ILP
// axes all null beyond this point).
// 2-way K-split, double-buffered LDS (ONE barrier/iter), VALU lsum + permlane.
// Softmax without max-tracking (Q pre-scaled by scale*log2e in Q-projection).
// Block = 512 thr = 8 waves: 4 q-groups x 2 K-halves. QBLK=128. grid = 512.
__global__ __launch_bounds__(512, 4)
void attn_mfma32(const unsigned short* __restrict__ Qbf,
                 const unsigned short* __restrict__ Kbf,
                 const unsigned short* __restrict__ Vbf,
                 unsigned short* __restrict__ Aout)
{
  __shared__ __attribute__((aligned(16))) char smem[32768];

  const int id = blockIdx.x;
  const int bh = id & 15;                  // XCD-friendly: 2 heads per XCD L2
  const int b = bh >> 3, hd = bh & 7;
  const int t = threadIdx.x;
  const int w = t >> 6, l = t & 63;
  const int r = l & 31, hi = l >> 5;
  const int qg = w >> 1, kh = w & 1;       // q-group, K-half

  const unsigned short* Qb = Qbf + (size_t)b * kN * kC;
  const unsigned short* Kb = Kbf + (size_t)b * kN * kC;
  const unsigned short* Vb = Vbf + ((size_t)b * kC + hd * kHD) * kN;
  unsigned short* Ap = Aout + (size_t)b * kN * kC;

  const int q0 = (id >> 4) * 128 + qg * 32;

  const bf16x8 qf0 = *(const bf16x8*)&Qb[(size_t)(q0 + r) * kC + hd * kHD + hi * 8];
  const bf16x8 qf1 = *(const bf16x8*)&Qb[(size_t)(q0 + r) * kC + hd * kHD + 16 + hi * 8];

  const int tt = t & 255, th = t >> 8;
  const unsigned short* ksrc = Kb + (size_t)(th * 2048 + (tt >> 2)) * kC + hd * kHD + (tt & 3) * 8;
  const unsigned short* vsrc = Vb + (size_t)(tt >> 3) * kN + th * 2048 + (tt & 7) * 8;
  char* kdst = smem + th * 4096 + ((tt & 3) * 64 + ((tt >> 2) ^ (9 * (tt & 3)))) * 16;
  char* vdst = smem + 8192 + th * 4096 + ((tt & 7) * 32 + ((tt >> 3) ^ (tt & 7))) * 16;

  int koff[2][2], voff[2][2];
#pragma unroll
  for (int ds = 0; ds < 2; ++ds)
#pragma unroll
    for (int tile = 0; tile < 2; ++tile) {
      const int c = 2 * ds + hi;
      koff[ds][tile] = kh * 4096 + (c * 64 + tile * 32 + (r ^ (9 * c))) * 16;
    }
#pragma unroll
  for (int ktile = 0; ktile < 2; ++ktile)
#pragma unroll
    for (int kc = 0; kc < 2; ++kc) {
      const int c = ktile * 4 + kc * 2 + hi;
      voff[ktile][kc] = 8192 + kh * 4096 + (c * 32 + (r ^ c)) * 16;
    }

  const f32x16 ZV = {0.f};
  f32x16 oA = ZV, oB = ZV;
  float lsum = 0.f;

  bf16x8 krg = *(const bf16x8*)ksrc;
  bf16x8 vrg = *(const bf16x8*)vsrc;

  for (int it = 0; it < 32; ++it) {
    const int bo = (it & 1) << 14;         // double-buffer byte offset
    *(bf16x8*)(kdst + bo) = krg;
    *(bf16x8*)(vdst + bo) = vrg;
    if (it + 1 < 32) {
      krg = *(const bf16x8*)(ksrc + (size_t)(it + 1) * 64 * kC);
      vrg = *(const bf16x8*)(vsrc + (it + 1) * 64);
    }
    __syncthreads();

    bf16x8 ka00 = *(const bf16x8*)(smem + bo + koff[0][0]);
    bf16x8 ka10 = *(const bf16x8*)(smem + bo + koff[1][0]);
    bf16x8 ka01 = *(const bf16x8*)(smem + bo + koff[0][1]);
    bf16x8 ka11 = *(const bf16x8*)(smem + bo + koff[1][1]);
    __builtin_amdgcn_s_setprio(1);
    f32x16 s0 = __builtin_amdgcn_mfma_f32_32x32x16_bf16(ka00, qf0, ZV, 0, 0, 0);
    s0        = __builtin_amdgcn_mfma_f32_32x32x16_bf16(ka10, qf1, s0, 0, 0, 0);
    f32x16 s1 = __builtin_amdgcn_mfma_f32_32x32x16_bf16(ka01, qf0, ZV, 0, 0, 0);
    s1        = __builtin_amdgcn_mfma_f32_32x32x16_bf16(ka11, qf1, s1, 0, 0, 0);
    __builtin_amdgcn_s_setprio(0);

#pragma unroll
    for (int ktile = 0; ktile < 2; ++ktile) {
      const f32x16& sv = ktile ? s1 : s0;
      float pe[16];
#pragma unroll
      for (int j = 0; j < 16; ++j) pe[j] = exp2_hw(sv[j]);
      lsum += (((pe[0] + pe[1]) + (pe[2] + pe[3])) + ((pe[4] + pe[5]) + (pe[6] + pe[7])))
            + (((pe[8] + pe[9]) + (pe[10] + pe[11])) + ((pe[12] + pe[13]) + (pe[14] + pe[15])));
      const unsigned c0 = cvt_pk_bf16(pe[0], pe[1]),   c1 = cvt_pk_bf16(pe[2], pe[3]);
      const unsigned c2 = cvt_pk_bf16(pe[4], pe[5]),   c3 = cvt_pk_bf16(pe[6], pe[7]);
      const unsigned c4 = cvt_pk_bf16(pe[8], pe[9]),   c5 = cvt_pk_bf16(pe[10], pe[11]);
      const unsigned c6 = cvt_pk_bf16(pe[12], pe[13]), c7 = cvt_pk_bf16(pe[14], pe[15]);
      auto a02 = __builtin_amdgcn_permlane32_swap(c0, c2, false, false);
      auto a13 = __builtin_amdgcn_permlane32_swap(c1, c3, false, false);
      auto a46 = __builtin_amdgcn_permlane32_swap(c4, c6, false, false);
      auto a57 = __builtin_amdgcn_permlane32_swap(c5, c7, false, false);
      union { unsigned u[4]; bf16x8 v; } p0, p1;
      p0.u[0] = a02[0]; p0.u[1] = a13[0]; p0.u[2] = a02[1]; p0.u[3] = a13[1];
      p1.u[0] = a46[0]; p1.u[1] = a57[0]; p1.u[2] = a46[1]; p1.u[3] = a57[1];
      bf16x8 vf0 = *(const bf16x8*)(smem + bo + voff[ktile][0]);
      bf16x8 vf1 = *(const bf16x8*)(smem + bo + voff[ktile][1]);
      __builtin_amdgcn_s_setprio(1);
      oA = __builtin_amdgcn_mfma_f32_32x32x16_bf16(vf0, p0.v, oA, 0, 0, 0);
      oB = __builtin_amdgcn_mfma_f32_32x32x16_bf16(vf1, p1.v, oB, 0, 0, 0);
      __builtin_amdgcn_s_setprio(0);
    }
  }

  {
    auto pr = __builtin_amdgcn_permlane32_swap(
        __builtin_bit_cast(unsigned, lsum), __builtin_bit_cast(unsigned, lsum), false, false);
    lsum = __builtin_bit_cast(float, (unsigned)pr[0]) + __builtin_bit_cast(float, (unsigned)pr[1]);
  }
  float oS[16];
#pragma unroll
  for (int j = 0; j < 16; ++j) oS[j] = oA[j] + oB[j];

  float* Scr = (float*)smem;               // [4][64][17], aliased over staging
  __syncthreads();
  if (kh == 1) {
    float* S = Scr + ((size_t)qg * 64 + l) * 17;
#pragma unroll
    for (int j = 0; j < 16; ++j) S[j] = oS[j];
    S[16] = lsum;
  }
  __syncthreads();
  if (kh == 0) {
    const float* S = Scr + ((size_t)qg * 64 + l) * 17;
#pragma unroll
    for (int j = 0; j < 16; ++j) oS[j] += S[j];
    lsum += S[16];
    const float inv = 1.f / lsum;

    unsigned* T = (unsigned*)(Scr + (size_t)qg * 64 * 17);
#pragma unroll
    for (int p = 0; p < 8; ++p) {
      const int r2 = 4 * (p >> 1) + 2 * hi + (p & 1);
      T[r2 * 33 + r] = cvt_pk_bf16(oS[2 * p] * inv, oS[2 * p + 1] * inv);
    }
    unsigned v[8];
#pragma unroll
    for (int j = 0; j < 8; ++j) v[j] = T[(8 * hi + j) * 33 + r];
    unsigned short* outp = Ap + (size_t)(q0 + r) * kC + hd * kHD + hi * 16;
    uint4 w0{v[0], v[1], v[2], v[3]}, w1{v[4], v[5], v[6], v[7]};
    *(uint4*)outp = w0;
    *(uint4*)(outp + 8) = w1;
  }
}

}  // namespace

extern "C" void kernel_launch(void* const* d_in, const int* in_sizes, int n_in,
                              void* d_out, int out_size, void* d_ws, size_t ws_size,
                              hipStream_t stream)
{
  const float* qfeat = (const float*)d_in[0];
  const float* lfeat = (const float*)d_in[1];
  const float* Wq = (const float*)d_in[2];
  const float* bq = (const float*)d_in[3];
  const float* Wk = (const float*)d_in[4];
  const float* bk = (const float*)d_in[5];
  const float* Wv = (const float*)d_in[6];
  const float* bv = (const float*)d_in[7];
  const float* Wo = (const float*)d_in[8];
  const float* bo = (const float*)d_in[9];
  const float* W1 = (const float*)d_in[10];
  const float* b1 = (const float*)d_in[11];
  const float* W2 = (const float*)d_in[12];
  const float* b2 = (const float*)d_in[13];
  float* out = (float*)d_out;
  (void)in_sizes; (void)n_in; (void)out_size; (void)ws_size;

  constexpr float kScaleLog2e = 0.25506970f;  // (1/sqrt(32)) * log2(e)

  const size_t bcn = (size_t)kB * kC * kN;  // 2,097,152
  unsigned short* qtok   = (unsigned short*)d_ws;   // bf16 (B,N,C) of query_feat
  unsigned short* ltok   = qtok + bcn;              // bf16 (B,N,C) of lateral_feat
  unsigned short* wbf    = ltok + bcn;              // bf16 weights, 786432
  unsigned short* qbf    = wbf + 786432;            // Q  bf16 (B,N,C), pre-scaled
  unsigned short* kbf    = qbf + bcn;               // K  bf16 (B,N,C)
  unsigned short* vbf    = kbf + bcn;               // V  bf16 (B,C,N)
  unsigned short* atok   = vbf + bcn;               // attn out bf16 (B,N,C)
  unsigned short* owstok = atok + bcn;              // attn block out bf16 (B,N,C)
  unsigned short* h1tok  = owstok + bcn;            // MLP hidden bf16 (B,N,4C)

  dim3 blk(256);

  convert_all<<<dim3(128, 8, 5), blk, 0, stream>>>(
      qfeat, lfeat, Wq, Wk, Wv, Wo, W1, W2, qtok, ltok, wbf);

  // fused Q (pre-scaled) + K/V projections
  gemm_qkv<<<dim3(64, 12, 2), blk, 0, stream>>>(
      wbf, qtok, ltok, bq, bk, bv, qbf, kbf, vbf, kScaleLog2e);

  attn_mfma32<<<dim3(512), dim3(512), 0, stream>>>(qbf, kbf, vbf, atok);

  // O-proj + residual(qtok bf16) -> bf16 token-major
  gemm_mfma<7, false, false><<<dim3(64, 4, 2), blk, 0, stream>>>(
      wbf + 196608, atok, bo, nullptr, owstok, qtok, kC, kN, kC, 1.0f);
  gemm_mfma<1, true, false><<<dim3(64, 16, 2), blk, 0, stream>>>(
      wbf + 262144, owstok, b1, nullptr, h1tok, nullptr, kC4, kN, kC, 1.0f);
  // MLP2: f32 out + residual read from owstok (bf16 tok-major)
  gemm_mfma<6, false, false><<<dim3(64, 4, 2), blk, 0, stream>>>(
      wbf + 524288, h1tok, b2, nullptr, out, owstok, kC, kN, kC4, 1.0f);
}